// Round 11
// baseline (188.814 us; speedup 1.0000x reference)
//
#include <hip/hip_runtime.h>
#include <stdint.h>

#define IN_DIM 512
#define CB 8192
#define CD 16
#define NROWS 32768
#define DELTAQ 8e-3f
#define FMAXV 3.402823466e38f

typedef short bf16x8 __attribute__((ext_vector_type(8)));
typedef float f32x4 __attribute__((ext_vector_type(4)));

__device__ inline unsigned short f2bf(float x) {
    unsigned u = __float_as_uint(x);
    unsigned r = u + 0x7FFFu + ((u >> 16) & 1u);   // RNE
    return (unsigned short)(r >> 16);
}
__device__ inline float bf2f(unsigned short h) { return __uint_as_float(((unsigned)h) << 16); }
__device__ inline unsigned umin32(unsigned a, unsigned b) { return a < b ? a : b; }
__device__ inline unsigned umax32(unsigned a, unsigned b) { return a > b ? a : b; }
__device__ inline unsigned long long shfl_xor_u64(unsigned long long x, int m) {
    double d = __shfl_xor(__longlong_as_double((long long)x), m, 64);
    return (unsigned long long)__double_as_longlong(d);
}

// ---------------- K0: csq (R1-bit-exact) + csq+256 + packed B fragments + counter ----------------
// Bp = [c1 | c2] in the two K-halves of one 16x16x32 B-fragment.
__global__ __launch_bounds__(256) void prep_kernel(const float* __restrict__ cb,
                                                   float* __restrict__ csq,
                                                   float* __restrict__ csqoff,
                                                   bf16x8* __restrict__ Bp,
                                                   int* __restrict__ counter) {
    int id = blockIdx.x * 256 + threadIdx.x;  // 0..32767
    if (id == 0) counter[0] = 0;
    if (id < CB) {   // SOURCE-IDENTICAL csq expression (bit-exact vs R1)
        const float4* p = (const float4*)(cb + (size_t)id * CD);
        float s = 0.f;
#pragma unroll
        for (int j = 0; j < 4; ++j) {
            float4 v = p[j];
            s += v.x * v.x + v.y * v.y + v.z * v.z + v.w * v.w;
        }
        csq[id] = s;
        csqoff[id] = s + 256.0f;   // positive-score offset for packed keys (approx path only)
    }
    int slot = id & 63;
    int nt = id >> 6;
    int q = slot >> 4;
    int n = nt * 16 + (slot & 15);
    int d0 = (q & 1) * 8;
    bool lo = (q < 2);          // k<16 -> c1[d], k>=16 -> c2[d]
    const float* src = cb + (size_t)n * CD + d0;
    bf16x8 v;
#pragma unroll
    for (int j = 0; j < 8; ++j) {
        float x = src[j];
        unsigned short a = f2bf(x);
        unsigned short b = f2bf(x - bf2f(a));
        v[j] = (short)(lo ? a : b);
    }
    Bp[id] = v;
}

// ---------------- K1: projection partials — sacred DAG; W via global (L1), LDS diet ----------------
// Block (strip, c): 64 rows x chunk c (128 dims). Input chunk staged in LDS
// (transposed + XOR swizzle: writes & reads both <=2-way per 16-lane phase = free).
// W read from global: per-wave-constant addresses -> 1 line per load, L1-resident,
// tracked by vmcnt (decoupled from the ds lgkm stream). Serial j-fold (R1 DAG).
__global__ __launch_bounds__(256) void proj_partial_kernel(const float* __restrict__ in,
                                                           const float* __restrict__ W,
                                                           float* __restrict__ partials) {
    __shared__ float4 LIN[2048];        // [o=0..31][r=0..63] swizzled
    int tid = threadIdx.x;
    int lane = tid & 63;
    int dg = tid >> 6;                  // NOT readfirstlane: keep W loads on the vector path
    int strip = blockIdx.x >> 2;
    int c = blockIdx.x & 3;
    int rowbase = strip * 64;
    const float4* inp4 = (const float4*)in;
    const float4* W4 = (const float4*)W;

    // stage input chunk: 64 rows x 32 f4, transposed-swizzled (global coalesced)
#pragma unroll
    for (int u = 0; u < 8; ++u) {
        int f = tid + u * 256;          // 0..2047
        int o = f & 31, r = f >> 5;
        LIN[o * 64 + (r ^ (o & 7))] = inp4[(size_t)(rowbase + r) * 128 + c * 32 + o];
    }
    __syncthreads();

    float acc[4];
#pragma unroll
    for (int i = 0; i < 4; ++i) acc[i] = 0.f;
#pragma unroll 4
    for (int j = 0; j < 32; ++j) {
        float4 v = LIN[j * 64 + (lane ^ (j & 7))];
#pragma unroll
        for (int i = 0; i < 4; ++i) {
            float4 w = W4[(size_t)(4 * dg + i) * 128 + c * 32 + j];   // 1 line/wave, L1
            acc[i] += v.x * w.x + v.y * w.y + v.z * w.z + v.w * w.w;
        }
    }
    float* o = partials + (size_t)c * NROWS * CD + (size_t)(rowbase + lane) * CD + 4 * dg;
#pragma unroll
    for (int i = 0; i < 4; ++i) o[i] = acc[i];
}

// ---------------- K2: packed-B scan + inline combine, queue flags ----------------
// 1024 blocks x 512 thr; 32 rows/block (G=2); wave e scans eighth e (64 tiles).
// Combine folded in: t = -2*(((p0+p1)+p2)+p3)  (verbatim expression -> bit-identical t').
__global__ __launch_bounds__(512, 6) void scan_kernel(
        const float* __restrict__ partials, float* __restrict__ tprime,
        const float* __restrict__ csqoff, const bf16x8* __restrict__ Bp,
        int* __restrict__ out, int* __restrict__ queue, int* __restrict__ counter) {
    __shared__ float tbuf[32][17];
    __shared__ unsigned long long m_k[32][8];
    __shared__ unsigned m_s2[32][8];

    int tid = threadIdx.x;
    int lane = tid & 63;
    int e = __builtin_amdgcn_readfirstlane(tid >> 6);   // eighth 0..7
    int rowbase = blockIdx.x * 32;

    {   // inline combine (bit-exact lineage) + stage tbuf + store tprime for fallback
        const size_t P = (size_t)NROWS * CD;
        size_t base = (size_t)rowbase * CD + tid;
        float p0 = partials[base];
        float p1 = partials[P + base];
        float p2 = partials[2 * P + base];
        float p3 = partials[3 * P + base];
        float t = -2.f * (((p0 + p1) + p2) + p3);
        tbuf[tid >> 4][tid & 15] = t;
        tprime[base] = t;
    }
    __syncthreads();

    int q = lane >> 4;
    int col = lane & 15;
    int d0 = (q & 1) * 8;
    bool lo = (q < 2);

    bf16x8 A1[2], A2[2];   // per rowgroup: A1=[t1|t1], A2=[t2|0]
#pragma unroll
    for (int g = 0; g < 2; ++g) {
        int arow = 16 * g + col;
#pragma unroll
        for (int j = 0; j < 8; ++j) {
            float x = tbuf[arow][d0 + j];
            unsigned short t1 = f2bf(x);
            unsigned short t2 = f2bf(x - bf2f(t1));
            A1[g][j] = (short)t1;
            A2[g][j] = (short)(lo ? t2 : 0);
        }
    }

    unsigned s1[2][4], s2[2][4];
#pragma unroll
    for (int g = 0; g < 2; ++g)
#pragma unroll
        for (int r = 0; r < 4; ++r) { s1[g][r] = 0xFFFFFFFFu; s2[g][r] = 0xFFFFFFFFu; }

    int nt0 = e * 64;
    const bf16x8* pb = Bp + (size_t)nt0 * 64 + lane;
    const float* csqp = csqoff + nt0 * 16 + col;

#pragma unroll 4
    for (int t = 0; t < 64; ++t) {
        bf16x8 b = pb[(size_t)t * 64];
        float cs = csqp[t * 16];
        f32x4 ini = {cs, cs, cs, cs};
        unsigned tt = (unsigned)t;
#pragma unroll
        for (int g = 0; g < 2; ++g) {
            f32x4 acc = __builtin_amdgcn_mfma_f32_16x16x32_bf16(A1[g], b, ini, 0, 0, 0);
            acc = __builtin_amdgcn_mfma_f32_16x16x32_bf16(A2[g], b, acc, 0, 0, 0);
#pragma unroll
            for (int r = 0; r < 4; ++r) {
                unsigned k = (__float_as_uint(acc[r]) & 0xFFFFFFC0u) | tt;
                s2[g][r] = umin32(s2[g][r], umax32(k, s1[g][r]));   // uses OLD s1
                s1[g][r] = umin32(s1[g][r], k);
            }
        }
    }

    // cross-col reduce; FK orders (qscore, e, tile, col) = (qscore, code)
#pragma unroll
    for (int g = 0; g < 2; ++g)
#pragma unroll
        for (int r = 0; r < 4; ++r) {
            unsigned long long FK = ((unsigned long long)(s1[g][r] & 0xFFFFFFC0u) << 13)
                                  | ((unsigned long long)e << 10)
                                  | ((unsigned long long)(s1[g][r] & 63u) << 4)
                                  | (unsigned long long)col;
            unsigned s2q = s2[g][r] & 0xFFFFFFC0u;
#pragma unroll
            for (int m = 1; m < 16; m <<= 1) {
                unsigned long long oFK = shfl_xor_u64(FK, m);
                unsigned os2 = (unsigned)__shfl_xor((int)s2q, m, 64);
                unsigned qa = (unsigned)(FK >> 13);
                unsigned qb = (unsigned)(oFK >> 13);
                s2q = umin32(umin32(s2q, os2), umax32(qa, qb));
                FK = oFK < FK ? oFK : FK;
            }
            if (col == 0) {
                int rl = 16 * g + 4 * q + r;   // C/D row = quad*4 + reg
                m_k[rl][e] = FK;
                m_s2[rl][e] = s2q;
            }
        }
    __syncthreads();

    if (tid < 32) {
        unsigned long long mFK = m_k[tid][0];
        unsigned g1 = (unsigned)(m_k[tid][0] >> 13);
        unsigned g2 = m_s2[tid][0];
#pragma unroll
        for (int ee = 1; ee < 8; ++ee) {
            unsigned long long F = m_k[tid][ee];
            unsigned u = (unsigned)(F >> 13);
            if (u < g1) { g2 = g1; g1 = u; } else { g2 = umin32(g2, u); }
            g2 = umin32(g2, m_s2[tid][ee]);
            mFK = F < mFK ? F : mFK;
        }
        int ccol = (int)(mFK & 15ull);
        int ctile = (int)((mFK >> 4) & 63ull);
        int ce = (int)((mFK >> 10) & 7ull);
        int row = rowbase + tid;
        out[row] = ((ce * 64 + ctile) << 4) | ccol;
        if (__uint_as_float(g2) - __uint_as_float(g1) < DELTAQ) {
            int pos = atomicAdd(counter, 1);
            queue[pos] = row;
        }
    }
}

// ---------------- K3: fallback — R1's fp32 arithmetic, bit-exact, queue-driven ----------------
__global__ __launch_bounds__(256) void fallback_kernel(const float* __restrict__ tprime,
                                                       const float* __restrict__ cb,
                                                       const float* __restrict__ csq,
                                                       const int* __restrict__ queue,
                                                       const int* __restrict__ counter,
                                                       int* __restrict__ out) {
    __shared__ unsigned long long red[4];
    int nq = counter[0];
    int tid = threadIdx.x;
    int lane = tid & 63;
    int w = tid >> 6;

    for (int qi = blockIdx.x; qi < nq; qi += 256) {
        int row = queue[qi];
        float tp[16];
        const float* tpp = tprime + (size_t)row * CD;
#pragma unroll
        for (int d = 0; d < 16; ++d) tp[d] = tpp[d];   // uniform -> broadcast

        float best = FMAXV;
        int bidx = 0;
#pragma unroll 2
        for (int i = 0; i < 32; ++i) {
            int k = tid + 256 * i;            // ascending per thread
            const float* cp = cb + (size_t)k * CD;
            float s = csq[k];
#pragma unroll
            for (int d = 0; d < 16; ++d) s += tp[d] * cp[d];
            if (s < best) { best = s; bidx = k; }
        }
        unsigned u = __float_as_uint(best);
        u = (u & 0x80000000u) ? ~u : (u | 0x80000000u);
        unsigned long long key = ((unsigned long long)u << 32) | (unsigned)bidx;
#pragma unroll
        for (int m = 1; m < 64; m <<= 1) {
            unsigned long long o = shfl_xor_u64(key, m);
            key = o < key ? o : key;
        }
        if (lane == 0) red[w] = key;
        __syncthreads();
        if (tid == 0) {
            unsigned long long mm = red[0];
#pragma unroll
            for (int i = 1; i < 4; ++i) { unsigned long long x = red[i]; mm = x < mm ? x : mm; }
            out[row] = (int)(mm & 0xFFFFFFFFull);
        }
        __syncthreads();
    }
}

extern "C" void kernel_launch(void* const* d_in, const int* in_sizes, int n_in,
                              void* d_out, int out_size, void* d_ws, size_t ws_size,
                              hipStream_t stream) {
    const float* input = (const float*)d_in[0];  // (8,4096,512) fp32
    const float* W     = (const float*)d_in[1];  // (16,512) fp32
    const float* cb    = (const float*)d_in[2];  // (8192,16) fp32
    int* out = (int*)d_out;                      // (32768,) int32 labels

    float*  tprime   = (float*)d_ws;                      // 2 MB
    float*  csq      = tprime + (size_t)NROWS * CD;       // 32 KB
    float*  csqoff   = csq + CB;                          // 32 KB
    bf16x8* Bp       = (bf16x8*)(csqoff + CB);            // 512 KB
    float*  partials = (float*)(Bp + 32768);              // 8 MB
    int*    counter  = (int*)(partials + 4 * (size_t)NROWS * CD);
    int*    queue    = counter + 16;                      // 128 KB

    prep_kernel<<<32768 / 256, 256, 0, stream>>>(cb, csq, csqoff, Bp, counter);
    proj_partial_kernel<<<(NROWS / 64) * 4, 256, 0, stream>>>(input, W, partials);
    scan_kernel<<<NROWS / 32, 512, 0, stream>>>(partials, tprime, csqoff, Bp, out, queue, counter);
    fallback_kernel<<<256, 256, 0, stream>>>(tprime, cb, csq, queue, counter, out);
}

// Round 13
// 170.918 us; speedup vs baseline: 1.1047x; 1.1047x over previous
//
#include <hip/hip_runtime.h>
#include <stdint.h>

#define IN_DIM 512
#define CB 8192
#define CD 16
#define NROWS 32768
#define DELTAQ 5e-3f
#define FMAXV 3.402823466e38f

typedef short bf16x8 __attribute__((ext_vector_type(8)));
typedef float f32x4 __attribute__((ext_vector_type(4)));

__device__ inline unsigned short f2bf(float x) {
    unsigned u = __float_as_uint(x);
    unsigned r = u + 0x7FFFu + ((u >> 16) & 1u);   // RNE
    return (unsigned short)(r >> 16);
}
__device__ inline float bf2f(unsigned short h) { return __uint_as_float(((unsigned)h) << 16); }
__device__ inline unsigned umin32(unsigned a, unsigned b) { return a < b ? a : b; }
__device__ inline unsigned umax32(unsigned a, unsigned b) { return a > b ? a : b; }
__device__ inline unsigned long long shfl_xor_u64(unsigned long long x, int m) {
    double d = __shfl_xor(__longlong_as_double((long long)x), m, 64);
    return (unsigned long long)__double_as_longlong(d);
}

// ---------------- K0: csq (R1-bit-exact) + csq+256 + packed B fragments + counter ----------------
// Bp = [c1 | c2] in the two K-halves of one 16x16x32 B-fragment.  [verbatim R10]
__global__ __launch_bounds__(256) void prep_kernel(const float* __restrict__ cb,
                                                   float* __restrict__ csq,
                                                   float* __restrict__ csqoff,
                                                   bf16x8* __restrict__ Bp,
                                                   int* __restrict__ counter) {
    int id = blockIdx.x * 256 + threadIdx.x;  // 0..32767
    if (id == 0) counter[0] = 0;
    if (id < CB) {   // SOURCE-IDENTICAL csq expression (bit-exact vs R1)
        const float4* p = (const float4*)(cb + (size_t)id * CD);
        float s = 0.f;
#pragma unroll
        for (int j = 0; j < 4; ++j) {
            float4 v = p[j];
            s += v.x * v.x + v.y * v.y + v.z * v.z + v.w * v.w;
        }
        csq[id] = s;
        csqoff[id] = s + 256.0f;   // positive-score offset for packed keys (approx path only)
    }
    int slot = id & 63;
    int nt = id >> 6;
    int q = slot >> 4;
    int n = nt * 16 + (slot & 15);
    int d0 = (q & 1) * 8;
    bool lo = (q < 2);          // k<16 -> c1[d], k>=16 -> c2[d]
    const float* src = cb + (size_t)n * CD + d0;
    bf16x8 v;
#pragma unroll
    for (int j = 0; j < 8; ++j) {
        float x = src[j];
        unsigned short a = f2bf(x);
        unsigned short b = f2bf(x - bf2f(a));
        v[j] = (short)(lo ? a : b);
    }
    Bp[id] = v;
}

// ---------------- K1: projection partials — VERBATIM R10 (bit-proven t' lineage) ----------------
// Block (strip, c): 64 rows x chunk c (128 dims). W chunk-slice (16x128, 8 KB) and the
// input chunk both staged in LDS; inner loop has ZERO global/scalar loads.
// Input LDS layout transposed+XOR-swizzled: write [o][r^(o&7)], read [j][lane^(j&7)].
// Arithmetic: serial j-fold per chunk (R1 DAG).
__global__ __launch_bounds__(256) void proj_partial_kernel(const float* __restrict__ in,
                                                           const float* __restrict__ W,
                                                           float* __restrict__ partials) {
    __shared__ float4 LIN[2048];        // [o=0..31][r=0..63] swizzled
    __shared__ float4 WL[16 * 33];      // [d][j] with pad: row stride 33 f4
    int tid = threadIdx.x;
    int lane = tid & 63;
    int dg = __builtin_amdgcn_readfirstlane(tid >> 6);   // d-group: d in [4dg, 4dg+4)
    int strip = blockIdx.x >> 2;
    int c = blockIdx.x & 3;
    int rowbase = strip * 64;
    const float4* inp4 = (const float4*)in;
    const float4* W4 = (const float4*)W;

    // stage W slice: d rows 0..15, chunk c: 16 x 32 f4
#pragma unroll
    for (int u = 0; u < 2; ++u) {
        int f = tid + u * 256;          // 0..511
        int d = f >> 5, o = f & 31;
        WL[d * 33 + o] = W4[(size_t)d * 128 + c * 32 + o];
    }
    // stage input chunk: 64 rows x 32 f4, transposed-swizzled
#pragma unroll
    for (int u = 0; u < 8; ++u) {
        int f = tid + u * 256;          // 0..2047
        int o = f & 31, r = f >> 5;     // consecutive tid -> consecutive o: global coalesced
        LIN[o * 64 + (r ^ (o & 7))] = inp4[(size_t)(rowbase + r) * 128 + c * 32 + o];
    }
    __syncthreads();

    float acc[4];
#pragma unroll
    for (int i = 0; i < 4; ++i) acc[i] = 0.f;
#pragma unroll 4
    for (int j = 0; j < 32; ++j) {
        float4 v = LIN[j * 64 + (lane ^ (j & 7))];
#pragma unroll
        for (int i = 0; i < 4; ++i) {
            float4 w = WL[(4 * dg + i) * 33 + j];   // wave-uniform -> LDS broadcast
            acc[i] += v.x * w.x + v.y * w.y + v.z * w.z + v.w * w.w;
        }
    }
    float* o = partials + (size_t)c * NROWS * CD + (size_t)(rowbase + lane) * CD + 4 * dg;
#pragma unroll
    for (int i = 0; i < 4; ++i) o[i] = acc[i];
}

// ---------------- K2: packed-B scan + inline combine — VERBATIM R11 (passed) ----------------
// 1024 blocks x 512 thr; 32 rows/block (G=2); wave e scans eighth e (64 tiles).
// Combine folded in: t = -2*(((p0+p1)+p2)+p3)  (verbatim expression -> bit-identical t').
__global__ __launch_bounds__(512, 6) void scan_kernel(
        const float* __restrict__ partials, float* __restrict__ tprime,
        const float* __restrict__ csqoff, const bf16x8* __restrict__ Bp,
        int* __restrict__ out, int* __restrict__ queue, int* __restrict__ counter) {
    __shared__ float tbuf[32][17];
    __shared__ unsigned long long m_k[32][8];
    __shared__ unsigned m_s2[32][8];

    int tid = threadIdx.x;
    int lane = tid & 63;
    int e = __builtin_amdgcn_readfirstlane(tid >> 6);   // eighth 0..7
    int rowbase = blockIdx.x * 32;

    {   // inline combine (bit-exact lineage) + stage tbuf + store tprime for fallback
        const size_t P = (size_t)NROWS * CD;
        size_t base = (size_t)rowbase * CD + tid;
        float p0 = partials[base];
        float p1 = partials[P + base];
        float p2 = partials[2 * P + base];
        float p3 = partials[3 * P + base];
        float t = -2.f * (((p0 + p1) + p2) + p3);
        tbuf[tid >> 4][tid & 15] = t;
        tprime[base] = t;
    }
    __syncthreads();

    int q = lane >> 4;
    int col = lane & 15;
    int d0 = (q & 1) * 8;
    bool lo = (q < 2);

    bf16x8 A1[2], A2[2];   // per rowgroup: A1=[t1|t1], A2=[t2|0]
#pragma unroll
    for (int g = 0; g < 2; ++g) {
        int arow = 16 * g + col;
#pragma unroll
        for (int j = 0; j < 8; ++j) {
            float x = tbuf[arow][d0 + j];
            unsigned short t1 = f2bf(x);
            unsigned short t2 = f2bf(x - bf2f(t1));
            A1[g][j] = (short)t1;
            A2[g][j] = (short)(lo ? t2 : 0);
        }
    }

    unsigned s1[2][4], s2[2][4];
#pragma unroll
    for (int g = 0; g < 2; ++g)
#pragma unroll
        for (int r = 0; r < 4; ++r) { s1[g][r] = 0xFFFFFFFFu; s2[g][r] = 0xFFFFFFFFu; }

    int nt0 = e * 64;
    const bf16x8* pb = Bp + (size_t)nt0 * 64 + lane;
    const float* csqp = csqoff + nt0 * 16 + col;

#pragma unroll 4
    for (int t = 0; t < 64; ++t) {
        bf16x8 b = pb[(size_t)t * 64];
        float cs = csqp[t * 16];
        f32x4 ini = {cs, cs, cs, cs};
        unsigned tt = (unsigned)t;
#pragma unroll
        for (int g = 0; g < 2; ++g) {
            f32x4 acc = __builtin_amdgcn_mfma_f32_16x16x32_bf16(A1[g], b, ini, 0, 0, 0);
            acc = __builtin_amdgcn_mfma_f32_16x16x32_bf16(A2[g], b, acc, 0, 0, 0);
#pragma unroll
            for (int r = 0; r < 4; ++r) {
                unsigned k = (__float_as_uint(acc[r]) & 0xFFFFFFC0u) | tt;
                s2[g][r] = umin32(s2[g][r], umax32(k, s1[g][r]));   // uses OLD s1
                s1[g][r] = umin32(s1[g][r], k);
            }
        }
    }

    // cross-col reduce; FK orders (qscore, e, tile, col) = (qscore, code)
#pragma unroll
    for (int g = 0; g < 2; ++g)
#pragma unroll
        for (int r = 0; r < 4; ++r) {
            unsigned long long FK = ((unsigned long long)(s1[g][r] & 0xFFFFFFC0u) << 13)
                                  | ((unsigned long long)e << 10)
                                  | ((unsigned long long)(s1[g][r] & 63u) << 4)
                                  | (unsigned long long)col;
            unsigned s2q = s2[g][r] & 0xFFFFFFC0u;
#pragma unroll
            for (int m = 1; m < 16; m <<= 1) {
                unsigned long long oFK = shfl_xor_u64(FK, m);
                unsigned os2 = (unsigned)__shfl_xor((int)s2q, m, 64);
                unsigned qa = (unsigned)(FK >> 13);
                unsigned qb = (unsigned)(oFK >> 13);
                s2q = umin32(umin32(s2q, os2), umax32(qa, qb));
                FK = oFK < FK ? oFK : FK;
            }
            if (col == 0) {
                int rl = 16 * g + 4 * q + r;   // C/D row = quad*4 + reg
                m_k[rl][e] = FK;
                m_s2[rl][e] = s2q;
            }
        }
    __syncthreads();

    if (tid < 32) {
        unsigned long long mFK = m_k[tid][0];
        unsigned g1 = (unsigned)(m_k[tid][0] >> 13);
        unsigned g2 = m_s2[tid][0];
#pragma unroll
        for (int ee = 1; ee < 8; ++ee) {
            unsigned long long F = m_k[tid][ee];
            unsigned u = (unsigned)(F >> 13);
            if (u < g1) { g2 = g1; g1 = u; } else { g2 = umin32(g2, u); }
            g2 = umin32(g2, m_s2[tid][ee]);
            mFK = F < mFK ? F : mFK;
        }
        int ccol = (int)(mFK & 15ull);
        int ctile = (int)((mFK >> 4) & 63ull);
        int ce = (int)((mFK >> 10) & 7ull);
        int row = rowbase + tid;
        out[row] = ((ce * 64 + ctile) << 4) | ccol;
        if (__uint_as_float(g2) - __uint_as_float(g1) < DELTAQ) {
            int pos = atomicAdd(counter, 1);
            queue[pos] = row;
        }
    }
}

// ---------------- K3: fallback — R1's fp32 arithmetic, bit-exact, queue-driven ----------------
__global__ __launch_bounds__(256) void fallback_kernel(const float* __restrict__ tprime,
                                                       const float* __restrict__ cb,
                                                       const float* __restrict__ csq,
                                                       const int* __restrict__ queue,
                                                       const int* __restrict__ counter,
                                                       int* __restrict__ out) {
    __shared__ unsigned long long red[4];
    int nq = counter[0];
    int tid = threadIdx.x;
    int lane = tid & 63;
    int w = tid >> 6;

    for (int qi = blockIdx.x; qi < nq; qi += 256) {
        int row = queue[qi];
        float tp[16];
        const float* tpp = tprime + (size_t)row * CD;
#pragma unroll
        for (int d = 0; d < 16; ++d) tp[d] = tpp[d];   // uniform -> broadcast

        float best = FMAXV;
        int bidx = 0;
#pragma unroll 2
        for (int i = 0; i < 32; ++i) {
            int k = tid + 256 * i;            // ascending per thread
            const float* cp = cb + (size_t)k * CD;
            float s = csq[k];
#pragma unroll
            for (int d = 0; d < 16; ++d) s += tp[d] * cp[d];
            if (s < best) { best = s; bidx = k; }
        }
        unsigned u = __float_as_uint(best);
        u = (u & 0x80000000u) ? ~u : (u | 0x80000000u);
        unsigned long long key = ((unsigned long long)u << 32) | (unsigned)bidx;
#pragma unroll
        for (int m = 1; m < 64; m <<= 1) {
            unsigned long long o = shfl_xor_u64(key, m);
            key = o < key ? o : key;
        }
        if (lane == 0) red[w] = key;
        __syncthreads();
        if (tid == 0) {
            unsigned long long mm = red[0];
#pragma unroll
            for (int i = 1; i < 4; ++i) { unsigned long long x = red[i]; mm = x < mm ? x : mm; }
            out[row] = (int)(mm & 0xFFFFFFFFull);
        }
        __syncthreads();
    }
}

extern "C" void kernel_launch(void* const* d_in, const int* in_sizes, int n_in,
                              void* d_out, int out_size, void* d_ws, size_t ws_size,
                              hipStream_t stream) {
    const float* input = (const float*)d_in[0];  // (8,4096,512) fp32
    const float* W     = (const float*)d_in[1];  // (16,512) fp32
    const float* cb    = (const float*)d_in[2];  // (8192,16) fp32
    int* out = (int*)d_out;                      // (32768,) int32 labels

    float*  tprime   = (float*)d_ws;                      // 2 MB
    float*  csq      = tprime + (size_t)NROWS * CD;       // 32 KB
    float*  csqoff   = csq + CB;                          // 32 KB
    bf16x8* Bp       = (bf16x8*)(csqoff + CB);            // 512 KB
    float*  partials = (float*)(Bp + 32768);              // 8 MB
    int*    counter  = (int*)(partials + 4 * (size_t)NROWS * CD);
    int*    queue    = counter + 16;                      // 128 KB

    prep_kernel<<<32768 / 256, 256, 0, stream>>>(cb, csq, csqoff, Bp, counter);
    proj_partial_kernel<<<(NROWS / 64) * 4, 256, 0, stream>>>(input, W, partials);
    scan_kernel<<<NROWS / 32, 512, 0, stream>>>(partials, tprime, csqoff, Bp, out, queue, counter);
    fallback_kernel<<<256, 256, 0, stream>>>(tprime, cb, csq, queue, counter, out);
}